// Round 9
// baseline (259.875 us; speedup 1.0000x reference)
//
#include <hip/hip_runtime.h>
#include <stdint.h>

#define L2E 1.44269504088896f

static __device__ __forceinline__ float wsum(float v) {
    #pragma unroll
    for (int m = 1; m < 64; m <<= 1) v += __shfl_xor(v, m, 64);
    return v;
}
static __device__ __forceinline__ float sigm(float x) {
    return 1.0f / (1.0f + __builtin_amdgcn_exp2f(-x * L2E));
}
static __device__ __forceinline__ float tanh_(float x) {
    const float ax = fabsf(x);
    const float t = __builtin_amdgcn_exp2f(-2.0f * ax * L2E);
    const float r = (1.0f - t) / (1.0f + t);
    return (x < 0.f) ? -r : r;
}

// ---------------------------------------------------------------------------
// init: fused weight transpose (wihT/whhT/WkT) + slot broadcast + iter-0
// gkq/aux. grid 112 x 256 (28672 thr = exact transpose element count).
// ---------------------------------------------------------------------------
__global__ __launch_bounds__(256) void init_kernel(
    const float* __restrict__ s0,
    const float* __restrict__ lsg, const float* __restrict__ lsb,
    const float* __restrict__ Wq,  const float* __restrict__ Wk,
    const float* __restrict__ lig, const float* __restrict__ lib,
    const float* __restrict__ wih, const float* __restrict__ whh,
    float* __restrict__ slots, float* __restrict__ gkq, float* __restrict__ aux,
    float* __restrict__ wihT, float* __restrict__ whhT, float* __restrict__ WkT)
{
    __shared__ float wkT[4096];
    __shared__ float scr[4][64];
    const int tid = threadIdx.x, lane = tid & 63, wv = tid >> 6;
    const int idx = blockIdx.x * 256 + tid;

    if (idx < 12288) {
        const int i = idx / 192, j = idx - i * 192;
        wihT[idx] = wih[j * 64 + i];
    } else if (idx < 24576) {
        const int o = idx - 12288;
        const int i = o / 192, j = o - i * 192;
        whhT[o] = whh[j * 64 + i];
    } else {
        const int o = idx - 24576;
        const int p = o >> 6, d = o & 63;
        WkT[o] = Wk[d * 64 + p];
    }

    const int r = blockIdx.x * 4 + wv;          // 0..447
    const int s = r % 7;
    #pragma unroll
    for (int i = tid; i < 4096; i += 256) {
        const int d = i >> 6, p = i & 63;
        wkT[p * 64 + d] = Wk[i];
    }
    const float h = s0[s * 64 + lane];
    slots[r * 64 + lane] = h;
    __syncthreads();

    const float mean = wsum(h) * (1.0f / 64.0f);
    const float d = h - mean;
    const float var = wsum(d * d) * (1.0f / 64.0f);
    const float rs = rsqrtf(var + 1e-5f);
    const float sn = d * rs * lsg[lane] + lsb[lane];
    scr[wv][lane] = sn;
    __syncthreads();
    float q = 0.f;
    #pragma unroll 8
    for (int i = 0; i < 64; ++i) q = fmaf(scr[wv][i], Wq[i * 64 + lane], q);
    q *= 0.125f;
    __syncthreads();
    scr[wv][lane] = q;
    __syncthreads();
    float kq = 0.f;
    #pragma unroll 8
    for (int p = 0; p < 64; ++p) kq = fmaf(wkT[p * 64 + lane], scr[wv][p], kq);
    const float bk = wsum(lib[lane] * kq);
    const float gk = lig[lane] * kq;
    const float g1 = wsum(gk);
    gkq[r * 64 + lane] = gk;
    if (lane == 0) { aux[r * 2] = g1; aux[r * 2 + 1] = bk; }
}

// ---------------------------------------------------------------------------
// attn v3: lane = (row-slot r3 = lane>>3, dim-octet d3 = lane&7).
// gkq held in registers (7 s x 8 dims per lane, read once). x read directly
// from global, coalesced, exactly once; no LDS staging. Per j-iter (8 rows in
// flight across r3): octet partial sums -> shfl_xor(1,2,4) row reduce ->
// LN-folded logits -> softmax(+eps) -> Y[7][8] register accumulate (Phase B
// fused, same registers). Final shfl_xor(8,16,32) Y reduce + block reduce
// -> Ypart[b][chunk][456] (448 Y + 7 colsums + pad). grid B*16 = 1024 x 256.
// ---------------------------------------------------------------------------
__global__ __launch_bounds__(256) void attn_kernel(
    const float* __restrict__ x,
    const float* __restrict__ gkq, const float* __restrict__ aux,
    float* __restrict__ Ypart)
{
    __shared__ float ybuf[4][456];
    const int tid = threadIdx.x, lane = tid & 63, wv = tid >> 6;
    const int b = blockIdx.x >> 4, chunk = blockIdx.x & 15;
    const int d3 = lane & 7, r3 = lane >> 3;

    // gk slice -> registers (once): gkr[s][k] = gkq[b][s][d3*8+k]
    float gkr[7][8];
    #pragma unroll
    for (int s = 0; s < 7; ++s) {
        const float4 g0 = *(const float4*)(gkq + b * 448 + s * 64 + d3 * 8);
        const float4 g1 = *(const float4*)(gkq + b * 448 + s * 64 + d3 * 8 + 4);
        gkr[s][0] = g0.x; gkr[s][1] = g0.y; gkr[s][2] = g0.z; gkr[s][3] = g0.w;
        gkr[s][4] = g1.x; gkr[s][5] = g1.y; gkr[s][6] = g1.z; gkr[s][7] = g1.w;
    }
    // aux (wave-uniform -> scalar regs)
    float auxg[7], auxb[7];
    #pragma unroll
    for (int s = 0; s < 7; ++s) {
        auxg[s] = aux[b * 14 + 2 * s];
        auxb[s] = aux[b * 14 + 2 * s + 1];
    }

    const float* tb = x + (((long)b * 4096) + chunk * 256 + wv * 64) * 64;
    float Yacc[7][8];
    #pragma unroll
    for (int s = 0; s < 7; ++s)
        #pragma unroll
        for (int k = 0; k < 8; ++k) Yacc[s][k] = 0.f;
    float cacc[7] = {0.f, 0.f, 0.f, 0.f, 0.f, 0.f, 0.f};

    #pragma unroll 2
    for (int j = 0; j < 8; ++j) {
        // coalesced direct load: row j*8+r3, dims d3*8..d3*8+7
        const float* xr = tb + (j * 8 + r3) * 64 + d3 * 8;
        const float4 x0 = ((const float4*)xr)[0];
        const float4 x1 = ((const float4*)xr)[1];
        const float xf[8] = {x0.x, x0.y, x0.z, x0.w, x1.x, x1.y, x1.z, x1.w};

        float sum = 0.f, ss = 0.f;
        #pragma unroll
        for (int k = 0; k < 8; ++k) { sum += xf[k]; ss = fmaf(xf[k], xf[k], ss); }
        float as[7];
        #pragma unroll
        for (int s = 0; s < 7; ++s) {
            float a = 0.f;
            #pragma unroll
            for (int k = 0; k < 8; ++k) a = fmaf(xf[k], gkr[s][k], a);
            as[s] = a;
        }
        // reduce across the 8 dim-octets (masks 1,2 = DPP; 4 = swizzle)
        #pragma unroll
        for (int m = 1; m < 8; m <<= 1) {
            sum += __shfl_xor(sum, m, 64);
            ss  += __shfl_xor(ss, m, 64);
            #pragma unroll
            for (int s = 0; s < 7; ++s) as[s] += __shfl_xor(as[s], m, 64);
        }

        const float mean = sum * (1.0f / 64.0f);
        const float var  = ss * (1.0f / 64.0f) - mean * mean;
        const float rs   = rsqrtf(var + 1e-5f);
        const float rsm  = rs * mean;
        float t[7];
        #pragma unroll
        for (int s = 0; s < 7; ++s)
            t[s] = fmaf(rs, as[s], fmaf(-rsm, auxg[s], auxb[s]));
        float mx = t[0];
        #pragma unroll
        for (int s = 1; s < 7; ++s) mx = fmaxf(mx, t[s]);
        float e[7], se = 0.f;
        #pragma unroll
        for (int s = 0; s < 7; ++s) {
            e[s] = __builtin_amdgcn_exp2f((t[s] - mx) * L2E);
            se += e[s];
        }
        const float inv = 1.0f / se;
        float wrs[7];
        #pragma unroll
        for (int s = 0; s < 7; ++s) {
            const float w = fmaf(e[s], inv, 1e-8f);
            cacc[s] += w;                       // 8 d3-copies per row: /8 later
            wrs[s] = w * rs;
        }
        // Phase B fused: x still in registers
        #pragma unroll
        for (int s = 0; s < 7; ++s)
            #pragma unroll
            for (int k = 0; k < 8; ++k)
                Yacc[s][k] = fmaf(wrs[s], xf[k], Yacc[s][k]);
    }

    // reduce Yacc across the 8 row-slots
    #pragma unroll
    for (int m = 8; m < 64; m <<= 1)
        #pragma unroll
        for (int s = 0; s < 7; ++s)
            #pragma unroll
            for (int k = 0; k < 8; ++k)
                Yacc[s][k] += __shfl_xor(Yacc[s][k], m, 64);
    #pragma unroll
    for (int s = 0; s < 7; ++s) cacc[s] = wsum(cacc[s]) * 0.125f;

    if (r3 == 0) {
        #pragma unroll
        for (int s = 0; s < 7; ++s) {
            *(float4*)&ybuf[wv][s * 64 + d3 * 8] =
                make_float4(Yacc[s][0], Yacc[s][1], Yacc[s][2], Yacc[s][3]);
            *(float4*)&ybuf[wv][s * 64 + d3 * 8 + 4] =
                make_float4(Yacc[s][4], Yacc[s][5], Yacc[s][6], Yacc[s][7]);
        }
    }
    if (lane == 0) {
        #pragma unroll
        for (int s = 0; s < 7; ++s) ybuf[wv][448 + s] = cacc[s];
        ybuf[wv][455] = 0.f;
    }
    __syncthreads();
    for (int i = tid; i < 455; i += 256)
        Ypart[((long)b * 16 + chunk) * 456 + i] =
            ybuf[0][i] + ybuf[1][i] + ybuf[2][i] + ybuf[3][i];
}

// ---------------------------------------------------------------------------
// update v2 (R4-exact): one block (256 thr) per (b,s) row. All weight reads
// coalesced (wihT/whhT/WkT pre-transposed). Chain: Y/C reduce -> aoc ->
// u=(aoc@Wv) -> GRU -> MLP -> slots (+ next-iter LN/q/kq or final store).
// grid 448.
// ---------------------------------------------------------------------------
__global__ __launch_bounds__(256) void update_kernel(
    const float* __restrict__ Ypart, float* __restrict__ slots,
    const float* __restrict__ Wv,
    const float* __restrict__ wihT, const float* __restrict__ whhT,
    const float* __restrict__ bih,  const float* __restrict__ bhh,
    const float* __restrict__ w1,   const float* __restrict__ b1,
    const float* __restrict__ w2,   const float* __restrict__ b2,
    const float* __restrict__ lsg,  const float* __restrict__ lsb,
    const float* __restrict__ Wq,   const float* __restrict__ WkT,
    const float* __restrict__ lig,  const float* __restrict__ lib,
    float* __restrict__ gkq, float* __restrict__ aux,
    float* __restrict__ out, int last)
{
    __shared__ float red[4][64];
    __shared__ float c16[16];
    __shared__ float ash[64];
    __shared__ float ush[64];
    __shared__ float hsh[64];
    __shared__ float gish[192], ghsh[192];
    __shared__ float hnsh[64];
    __shared__ float mbsh[128];
    __shared__ float qsh[64];
    const int tid = threadIdx.x, lane = tid & 63, wv = tid >> 6;
    const int r = blockIdx.x;                   // 0..447
    const int b = r / 7, s = r - b * 7;
    const float* Yb = Ypart + (long)b * 16 * 456;

    float yp = 0.f;
    #pragma unroll
    for (int c = 0; c < 4; ++c)
        yp += Yb[(wv * 4 + c) * 456 + s * 64 + lane];
    red[wv][lane] = yp;
    if (tid < 16) c16[tid] = Yb[tid * 456 + 448 + s];
    if (tid >= 64 && tid < 128) hsh[tid - 64] = slots[r * 64 + (tid - 64)];
    __syncthreads();

    if (tid < 64) {                             // wave 0
        const float Yd = red[0][lane] + red[1][lane] + red[2][lane] + red[3][lane];
        float C = 0.f;
        #pragma unroll
        for (int c = 0; c < 16; ++c) C += c16[c];
        const float Z = wsum(Yd) * (1.0f / 64.0f);   // Z = sum_d Y / 64
        ash[lane] = (lig[lane] * (Yd - Z) + lib[lane] * C) / C;
    }
    __syncthreads();

    float up = 0.f;
    #pragma unroll
    for (int i = 0; i < 16; ++i) {
        const int ii = wv * 16 + i;
        up = fmaf(ash[ii], Wv[ii * 64 + lane], up);
    }
    red[wv][lane] = up;
    __syncthreads();
    if (tid < 64) ush[lane] = red[0][lane] + red[1][lane] + red[2][lane] + red[3][lane];
    __syncthreads();

    if (tid < 192) {
        float a1 = bih[tid], a2 = bhh[tid];
        #pragma unroll 8
        for (int i = 0; i < 64; ++i) {
            a1 = fmaf(ush[i], wihT[i * 192 + tid], a1);
            a2 = fmaf(hsh[i], whhT[i * 192 + tid], a2);
        }
        gish[tid] = a1; ghsh[tid] = a2;
    }
    __syncthreads();
    if (tid < 64) {
        const float rr = sigm(gish[tid] + ghsh[tid]);
        const float zz = sigm(gish[64 + tid] + ghsh[64 + tid]);
        const float nn = tanh_(gish[128 + tid] + rr * ghsh[128 + tid]);
        hnsh[tid] = (1.f - zz) * nn + zz * hsh[tid];
    }
    __syncthreads();

    if (tid < 128) {
        float m = b1[tid];
        #pragma unroll 8
        for (int i = 0; i < 64; ++i) m = fmaf(hnsh[i], w1[i * 128 + tid], m);
        mbsh[tid] = fmaxf(m, 0.f);
    }
    __syncthreads();

    if (tid < 64) {
        float o = b2[tid];
        #pragma unroll 8
        for (int t = 0; t < 128; ++t) o = fmaf(mbsh[t], w2[t * 64 + tid], o);
        const float snv = hnsh[tid] + o;
        slots[r * 64 + tid] = snv;
        if (last) {
            out[r * 64 + tid] = snv;
        } else {
            const float mean = wsum(snv) * (1.0f / 64.0f);
            const float d = snv - mean;
            const float var = wsum(d * d) * (1.0f / 64.0f);
            const float rs = rsqrtf(var + 1e-5f);
            const float sn = d * rs * lsg[tid] + lsb[tid];
            ash[tid] = sn;                       // wave0-internal reuse
            float q = 0.f;
            #pragma unroll 8
            for (int i = 0; i < 64; ++i) q = fmaf(ash[i], Wq[i * 64 + tid], q);
            qsh[tid] = q * 0.125f;
            float kq = 0.f;
            #pragma unroll 8
            for (int p = 0; p < 64; ++p) kq = fmaf(WkT[p * 64 + tid], qsh[p], kq);
            const float bk = wsum(lib[tid] * kq);
            const float gk = lig[tid] * kq;
            const float g1 = wsum(gk);
            gkq[r * 64 + tid] = gk;
            if (tid == 0) { aux[r * 2] = g1; aux[r * 2 + 1] = bk; }
        }
    }
}

// ---------------------------------------------------------------------------
extern "C" void kernel_launch(void* const* d_in, const int* in_sizes, int n_in,
                              void* d_out, int out_size, void* d_ws, size_t ws_size,
                              hipStream_t stream)
{
    const float* x   = (const float*)d_in[0];
    const float* lig = (const float*)d_in[1];
    const float* lib = (const float*)d_in[2];
    const float* lsg = (const float*)d_in[3];
    const float* lsb = (const float*)d_in[4];
    const float* s0  = (const float*)d_in[5];
    const float* Wk  = (const float*)d_in[6];
    const float* Wv  = (const float*)d_in[7];
    const float* Wq  = (const float*)d_in[8];
    const float* wih = (const float*)d_in[9];
    const float* whh = (const float*)d_in[10];
    const float* bih = (const float*)d_in[11];
    const float* bhh = (const float*)d_in[12];
    const float* w1  = (const float*)d_in[13];
    const float* b1  = (const float*)d_in[14];
    const float* w2  = (const float*)d_in[15];
    const float* b2  = (const float*)d_in[16];

    float* f = (float*)d_ws;
    float* gkq   = f; f += 448 * 64;
    float* aux   = f; f += 448 * 2;
    float* slots = f; f += 448 * 64;
    float* Ypart = f; f += (long)64 * 16 * 456;
    float* wihT  = f; f += 64 * 192;
    float* whhT  = f; f += 64 * 192;
    float* WkT   = f; f += 64 * 64;

    init_kernel<<<112, 256, 0, stream>>>(s0, lsg, lsb, Wq, Wk, lig, lib,
                                         wih, whh, slots, gkq, aux,
                                         wihT, whhT, WkT);
    for (int it = 0; it < 3; ++it) {
        attn_kernel<<<1024, 256, 0, stream>>>(x, gkq, aux, Ypart);
        update_kernel<<<448, 256, 0, stream>>>(
            Ypart, slots, Wv, wihT, whhT, bih, bhh, w1, b1, w2, b2,
            lsg, lsb, Wq, WkT, lig, lib, gkq, aux,
            (float*)d_out, it == 2);
    }
}